// Round 4
// baseline (114.690 us; speedup 1.0000x reference)
//
#include <hip/hip_runtime.h>
#include <math.h>

// Problem constants (match reference)
#define B_SZ    2048
#define IN_DIM  256
#define N_RULES 128
#define OUT_DIM 64
#define D_DIM   32896          // (IN_DIM+1)*N_RULES
#define NBIG    8192           // N_RULES*OUT_DIM (n = r*64 + o)
#define KAQ     512            // Aq row: [x^2 (256) | x (256)]

typedef __attribute__((ext_vector_type(8))) short bf16x8;
typedef __attribute__((ext_vector_type(4))) float f32x4;

static __device__ __forceinline__ short f2bf(float f) {
    union { float f; unsigned u; } v; v.f = f;
    unsigned r = v.u + 0x7fffu + ((v.u >> 16) & 1u);   // RNE
    return (short)(r >> 16);
}
static __device__ __forceinline__ void gld_lds16(const short* g, short* l) {
    __builtin_amdgcn_global_load_lds((const __attribute__((address_space(1))) void*)g,
                                     (__attribute__((address_space(3))) void*)l, 16, 0, 0);
}

// ---------------------------------------------------------------------------
// abq: blocks [0,128):   Bq[r][0:256]=bf16(-s), Bq[r][256:512]=bf16(2cs), k2[r]
//      blocks [128,384): Aq[b][0:256]=bf16(x^2), Aq[b][256:512]=bf16(x)
//      blocks [384,512): zero d_out (fusedgemm accumulates into it atomically)
// ---------------------------------------------------------------------------
__global__ __launch_bounds__(256) void abq_kernel(const float* __restrict__ X,
                                                  const float* __restrict__ centers,
                                                  const float* __restrict__ sigmas,
                                                  short* __restrict__ Aq,
                                                  short* __restrict__ Bq,
                                                  float* __restrict__ k2,
                                                  float* __restrict__ out) {
    int bid = blockIdx.x, t = threadIdx.x;
    if (bid < 128) {
        int r = bid, i = t;
        float sgm = sigmas[i * N_RULES + r];
        float s   = 0.5f / (sgm * sgm) + 1e-8f;
        float c   = centers[i * N_RULES + r];
        Bq[(size_t)r * KAQ + i]       = f2bf(-s);
        Bq[(size_t)r * KAQ + 256 + i] = f2bf(2.0f * c * s);
        __shared__ float red[256];
        red[i] = c * c * s;
        __syncthreads();
        for (int st = 128; st > 0; st >>= 1) {
            if (i < st) red[i] += red[i + st];
            __syncthreads();
        }
        if (i == 0) k2[r] = red[0];
    } else if (bid < 384) {
        int gid = (bid - 128) * 256 + t;     // 0..65535
        int i0 = gid * 8;                    // 8 consecutive elems, same X row
        int b = i0 >> 8, k = i0 & 255;
        float4 x0 = *(const float4*)(X + i0);
        float4 x1 = *(const float4*)(X + i0 + 4);
        bf16x8 q, v;
        q[0] = f2bf(x0.x * x0.x); v[0] = f2bf(x0.x);
        q[1] = f2bf(x0.y * x0.y); v[1] = f2bf(x0.y);
        q[2] = f2bf(x0.z * x0.z); v[2] = f2bf(x0.z);
        q[3] = f2bf(x0.w * x0.w); v[3] = f2bf(x0.w);
        q[4] = f2bf(x1.x * x1.x); v[4] = f2bf(x1.x);
        q[5] = f2bf(x1.y * x1.y); v[5] = f2bf(x1.y);
        q[6] = f2bf(x1.z * x1.z); v[6] = f2bf(x1.z);
        q[7] = f2bf(x1.w * x1.w); v[7] = f2bf(x1.w);
        *(bf16x8*)(Aq + (size_t)b * KAQ + k)       = q;
        *(bf16x8*)(Aq + (size_t)b * KAQ + 256 + k) = v;
    } else {
        int gid = (bid - 384) * 256 + t;     // 0..32767, one float4 each
        float4 z = {0.f, 0.f, 0.f, 0.f};
        *(float4*)(out + (size_t)gid * 4) = z;
    }
}

// ---------------------------------------------------------------------------
// rawprep: blocks [0,128)   — rawgemm+softmax+LN stats (16 batch rows/block);
//          blocks [128,1152) — prep (vectorized): Bmat bf16(gamma*W), Gp/Cp
//          partials, wr tail. Independent work packed into one launch so the
//          128 rawsm blocks hide under prep's 1024 bandwidth-bound blocks.
// ---------------------------------------------------------------------------
__global__ __launch_bounds__(256) void rawprep_kernel(const short* __restrict__ Aq,
                                                      const short* __restrict__ Bq,
                                                      const float* __restrict__ k2,
                                                      const float* __restrict__ X,
                                                      const float* __restrict__ gamma,
                                                      const float* __restrict__ beta,
                                                      const float* __restrict__ W,
                                                      float* __restrict__ frs,
                                                      float* __restrict__ muA,
                                                      float* __restrict__ rstdA,
                                                      short* __restrict__ Bmat,
                                                      float* __restrict__ wr,
                                                      float* __restrict__ Gp,
                                                      float* __restrict__ Cp) {
    __shared__ float S[16][132];     // rawsm scores (pad 132)
    __shared__ float sg[256], sc_[256];
    int bid = blockIdx.x, t = threadIdx.x;

    if (bid < 128) {
        // ---- rawsm: M=16,N=128,K=512 MFMA + softmax + LN stats ----
        int wave = t >> 6, lane = t & 63;
        int lrow = lane & 15, kq = lane >> 4;
        int m0 = bid * 16;

        f32x4 acc[2];
#pragma unroll
        for (int ni = 0; ni < 2; ++ni)
#pragma unroll
            for (int j = 0; j < 4; ++j) acc[ni][j] = 0.0f;

        const short* Ar = Aq + (size_t)(m0 + lrow) * KAQ + kq * 8;
        const short* Br = Bq + (size_t)(wave * 32 + lrow) * KAQ + kq * 8;
#pragma unroll
        for (int kt = 0; kt < 16; ++kt) {
            bf16x8 a = *(const bf16x8*)(Ar + kt * 32);
#pragma unroll
            for (int ni = 0; ni < 2; ++ni) {
                bf16x8 b = *(const bf16x8*)(Br + (size_t)ni * 16 * KAQ + kt * 32);
                acc[ni] = __builtin_amdgcn_mfma_f32_16x16x32_bf16(a, b, acc[ni], 0, 0, 0);
            }
        }
#pragma unroll
        for (int ni = 0; ni < 2; ++ni) {
            int col = wave * 32 + ni * 16 + lrow;
            float kk2 = k2[col];
#pragma unroll
            for (int j = 0; j < 4; ++j)
                S[kq * 4 + j][col] = (acc[ni][j] - kk2) * (1.0f / 256.0f);
        }
        __syncthreads();

#pragma unroll
        for (int rr = 0; rr < 4; ++rr) {
            int row = wave * 4 + rr;
            int b = m0 + row;
            float v0 = S[row][lane];
            float v1 = S[row][64 + lane];
            float m = fmaxf(v0, v1);
#pragma unroll
            for (int off = 32; off >= 1; off >>= 1) m = fmaxf(m, __shfl_xor(m, off));
            float e0 = expf(v0 - m), e1 = expf(v1 - m);
            float ssum = e0 + e1;
#pragma unroll
            for (int off = 32; off >= 1; off >>= 1) ssum += __shfl_xor(ssum, off);
            float inv = 1.0f / ssum;
            e0 *= inv; e1 *= inv;
            frs[(size_t)b * N_RULES + lane]      = e0;
            frs[(size_t)b * N_RULES + 64 + lane] = e1;
            float q = e0 * e0 + e1 * e1;
            float4 xv = *(const float4*)(X + (size_t)b * IN_DIM + lane * 4);
            float sx  = xv.x + xv.y + xv.z + xv.w;
            float sx2 = xv.x * xv.x + xv.y * xv.y + xv.z * xv.z + xv.w * xv.w;
#pragma unroll
            for (int off = 32; off >= 1; off >>= 1) {
                q   += __shfl_xor(q, off);
                sx  += __shfl_xor(sx, off);
                sx2 += __shfl_xor(sx2, off);
            }
            if (lane == 0) {
                float mu  = (sx + 1.0f) / (float)D_DIM;
                float var = (sx2 + 1.0f) * q / (float)D_DIM - mu * mu;
                muA[b]   = mu;
                rstdA[b] = rsqrtf(var + 1e-5f);
            }
        }
    } else {
        // ---- prep: 8 consecutive d per thread (vectorized) ----
        int pid = bid - 128;
        int c = pid & 15, o = pid >> 4;
        const float* Wo = W + (size_t)o * D_DIM;
        int d0 = c * 2048 + t * 8;
        float4 w0 = *(const float4*)(Wo + d0);
        float4 w1 = *(const float4*)(Wo + d0 + 4);
        float4 g0 = *(const float4*)(gamma + d0);
        float4 g1 = *(const float4*)(gamma + d0 + 4);
        float4 b0 = *(const float4*)(beta + d0);
        float4 b1 = *(const float4*)(beta + d0 + 4);
        float p0 = g0.x * w0.x, p1 = g0.y * w0.y, p2 = g0.z * w0.z, p3 = g0.w * w0.w;
        float p4 = g1.x * w1.x, p5 = g1.y * w1.y, p6 = g1.z * w1.z, p7 = g1.w * w1.w;
        float g = p0 + p1 + p2 + p3 + p4 + p5 + p6 + p7;
        float cc = b0.x * w0.x + b0.y * w0.y + b0.z * w0.z + b0.w * w0.w
                 + b1.x * w1.x + b1.y * w1.y + b1.z * w1.z + b1.w * w1.w;
        bf16x8 pv;
        pv[0] = f2bf(p0); pv[1] = f2bf(p1); pv[2] = f2bf(p2); pv[3] = f2bf(p3);
        pv[4] = f2bf(p4); pv[5] = f2bf(p5); pv[6] = f2bf(p6); pv[7] = f2bf(p7);
        int r = d0 >> 8, k = d0 & 255;
        *(bf16x8*)(Bmat + (size_t)((r << 6) + o) * IN_DIM + k) = pv;
        if (c == 15 && t < 128) {
            int d = 32768 + t;
            float w  = Wo[d];
            float ga = gamma[d];
            float be = beta[d];
            g += ga * w; cc += be * w;
            wr[t * 64 + o] = ga * w;
        }
        sg[t] = g; sc_[t] = cc;
        __syncthreads();
        for (int s = 128; s > 0; s >>= 1) {
            if (t < s) { sg[t] += sg[t + s]; sc_[t] += sc_[t + s]; }
            __syncthreads();
        }
        if (t == 0) { Gp[c * 64 + o] = sg[0]; Cp[c * 64 + o] = sc_[0]; }
    }
}

// ---------------------------------------------------------------------------
// fused gemm1 + weighted reduce + LN epilogue (T and P never materialized).
//   Grid (16 nc, 32 m-tiles) = 512 blocks, 2/CU (8 waves/CU).
//   A (64 rows x full K=256, 32 KB) staged ONCE; B double-buffered
//   (2 x 128x64, 32 KB). 16 phases (nt x kki): issue next B stage, counted
//   s_waitcnt vmcnt(4) (loads stay in flight across compute — NOT vmcnt(0)),
//   raw s_barrier (no implicit drain), 16 MFMA, barrier. After each nt's
//   4 phases, fold acc into oacc with frs/wr (registers only). Epilogue:
//   atomicAdd rstd-scaled partials directly into out (split-K style);
//   nc==0 blocks add the constant term -rstd*mu*G + C + bias once.
// ---------------------------------------------------------------------------
__global__ __launch_bounds__(256, 2) void fusedgemm_kernel(const short* __restrict__ Aq,
                                                           const short* __restrict__ Bmat,
                                                           const float* __restrict__ frs,
                                                           const float* __restrict__ wr,
                                                           const float* __restrict__ muA,
                                                           const float* __restrict__ rstdA,
                                                           const float* __restrict__ Gp,
                                                           const float* __restrict__ Cp,
                                                           const float* __restrict__ bias,
                                                           float* __restrict__ out) {
    __shared__ __attribute__((aligned(16))) short As[64 * 256];      // 32 KB, full K
    __shared__ __attribute__((aligned(16))) short Bs[2][128 * 64];   // 2 x 16 KB
    __shared__ float frs_s[64][9];    // stride 9: conflict-free broadcast reads

    int nc = blockIdx.x;              // rules nc*8 .. nc*8+7
    int m0 = blockIdx.y * 64;
    int t = threadIdx.x;
    int lane = t & 63, wave = t >> 6;
    int wm = wave >> 1, wn = wave & 1;
    int lrow = lane & 15, kq = lane >> 4;

    // stage frs for 64 rows x 8 rules (explicit lgkmcnt(0) before 1st barrier)
    for (int u = t; u < 64 * 8; u += 256) {
        int row = u >> 3, rr = u & 7;
        frs_s[row][rr] = frs[(size_t)(m0 + row) * N_RULES + nc * 8 + rr];
    }

    // prologue: stage full A (8 sweeps, 32 granules/row XOR swizzle) + B tile 0
#pragma unroll
    for (int s = 0; s < 8; ++s) {
        int idx = s * 256 + t;
        int row = idx >> 5, gp = idx & 31;
        int kg = gp ^ (row & 31);
        gld_lds16(Aq + (size_t)(m0 + row) * KAQ + 256 + kg * 8, As + idx * 8);
    }
#pragma unroll
    for (int s = 0; s < 4; ++s) {
        int idx = s * 256 + t;
        int row = idx >> 3, gp = idx & 7;
        int kg = gp ^ (row & 7);
        gld_lds16(Bmat + (size_t)(nc * 512 + row) * IN_DIM + kg * 8, Bs[0] + idx * 8);
    }

    f32x4 acc[2][4], oacc[2][4];
#pragma unroll
    for (int mi = 0; mi < 2; ++mi)
#pragma unroll
        for (int ni = 0; ni < 4; ++ni)
#pragma unroll
            for (int j = 0; j < 4; ++j) { acc[mi][ni][j] = 0.0f; oacc[mi][ni][j] = 0.0f; }

#pragma unroll
    for (int p = 0; p < 16; ++p) {
        int nt = p >> 2, kki = p & 3;
        if (p < 15) {
            int pn = p + 1;
            int n0n = nc * 512 + (pn >> 2) * 128;
            int kkn = (pn & 3) * 64;
            short* dst = Bs[pn & 1];
#pragma unroll
            for (int s = 0; s < 4; ++s) {
                int idx = s * 256 + t;
                int row = idx >> 3, gp = idx & 7;
                int kg = gp ^ (row & 7);
                gld_lds16(Bmat + (size_t)(n0n + row) * IN_DIM + kkn + kg * 8, dst + idx * 8);
            }
        }
        if (p == 0)       asm volatile("s_waitcnt vmcnt(4) lgkmcnt(0)" ::: "memory");
        else if (p < 15)  asm volatile("s_waitcnt vmcnt(4)" ::: "memory");
        else              asm volatile("s_waitcnt vmcnt(0)" ::: "memory");
        __builtin_amdgcn_s_barrier();
        asm volatile("" ::: "memory");

        const short* Bcur = Bs[p & 1];
        __builtin_amdgcn_s_setprio(1);
#pragma unroll
        for (int ks = 0; ks < 2; ++ks) {
            bf16x8 a[2], bb[4];
#pragma unroll
            for (int mi = 0; mi < 2; ++mi) {
                int row = wm * 32 + mi * 16 + lrow;
                a[mi] = *(const bf16x8*)(As + row * 256 + (((kki * 8 + ks * 4 + kq) ^ (row & 31)) * 8));
            }
#pragma unroll
            for (int ni = 0; ni < 4; ++ni) {
                int row = wn * 64 + ni * 16 + lrow;
                bb[ni] = *(const bf16x8*)(Bcur + row * 64 + (((ks * 4 + kq) ^ (row & 7)) * 8));
            }
#pragma unroll
            for (int mi = 0; mi < 2; ++mi)
#pragma unroll
                for (int ni = 0; ni < 4; ++ni)
                    acc[mi][ni] = __builtin_amdgcn_mfma_f32_16x16x32_bf16(a[mi], bb[ni], acc[mi][ni], 0, 0, 0);
        }
        __builtin_amdgcn_s_setprio(0);

        if (kki == 3) {
            // fold this tile's quadrant into oacc (registers only)
            int r  = nc * 8 + nt * 2 + wn;   // this wave's rule for tile nt
            int rr = nt * 2 + wn;
#pragma unroll
            for (int ni = 0; ni < 4; ++ni) {
                int o = ni * 16 + lrow;
                float wv = wr[(size_t)r * 64 + o];
#pragma unroll
                for (int mi = 0; mi < 2; ++mi) {
#pragma unroll
                    for (int j = 0; j < 4; ++j) {
                        int row = wm * 32 + mi * 16 + kq * 4 + j;
                        oacc[mi][ni][j] += frs_s[row][rr] * (acc[mi][ni][j] + wv);
                        acc[mi][ni][j] = 0.0f;
                    }
                }
            }
        }
        asm volatile("" ::: "memory");
        __builtin_amdgcn_s_barrier();
        asm volatile("" ::: "memory");
    }

    // epilogue: rstd-scaled atomic accumulate into out (both waves, no LDS pass)
#pragma unroll
    for (int mi = 0; mi < 2; ++mi) {
#pragma unroll
        for (int j = 0; j < 4; ++j) {
            int b = m0 + wm * 32 + mi * 16 + kq * 4 + j;
            float rs = rstdA[b];
#pragma unroll
            for (int ni = 0; ni < 4; ++ni)
                atomicAdd(out + (size_t)b * OUT_DIM + ni * 16 + lrow, rs * oacc[mi][ni][j]);
        }
    }
    // constant term, added exactly once per (b,o) by the nc==0 blocks
    if (nc == 0) {
        int o = t & 63, rb = t >> 6;
        float g = 0.f, cc = 0.f;
#pragma unroll
        for (int j = 0; j < 16; ++j) { g += Gp[j * 64 + o]; cc += Cp[j * 64 + o]; }
        cc += bias[o];
#pragma unroll
        for (int u = 0; u < 16; ++u) {
            int b = m0 + rb * 16 + u;
            atomicAdd(out + (size_t)b * OUT_DIM + o, cc - rstdA[b] * muA[b] * g);
        }
    }
}

// ---------------------------------------------------------------------------
extern "C" void kernel_launch(void* const* d_in, const int* in_sizes, int n_in,
                              void* d_out, int out_size, void* d_ws, size_t ws_size,
                              hipStream_t stream) {
    const float* X       = (const float*)d_in[0];
    const float* centers = (const float*)d_in[1];
    const float* sigmas  = (const float*)d_in[2];
    const float* gamma   = (const float*)d_in[3];
    const float* beta    = (const float*)d_in[4];
    const float* W       = (const float*)d_in[5];
    const float* bias    = (const float*)d_in[6];
    float* out = (float*)d_out;

    char* w = (char*)d_ws;
    short* Aq   = (short*)w; w += (size_t)B_SZ * KAQ * 2;           // 2 MB
    short* Bmat = (short*)w; w += (size_t)NBIG * IN_DIM * 2;        // 4 MB
    short* Bq   = (short*)w; w += (size_t)N_RULES * KAQ * 2;        // 128 KB
    float* frs  = (float*)w; w += (size_t)B_SZ * N_RULES * 4;       // 1 MB
    float* wr   = (float*)w; w += (size_t)NBIG * 4;
    float* k2   = (float*)w; w += (size_t)N_RULES * 4;
    float* muA  = (float*)w; w += (size_t)B_SZ * 4;
    float* rstdA= (float*)w; w += (size_t)B_SZ * 4;
    float* Gp   = (float*)w; w += (size_t)16 * 64 * 4;
    float* Cp   = (float*)w; w += (size_t)16 * 64 * 4;

    abq_kernel<<<512, 256, 0, stream>>>(X, centers, sigmas, Aq, Bq, k2, out);
    rawprep_kernel<<<1152, 256, 0, stream>>>(Aq, Bq, k2, X, gamma, beta, W,
                                             frs, muA, rstdA, Bmat, wr, Gp, Cp);
    fusedgemm_kernel<<<dim3(16, 32), 256, 0, stream>>>(Aq, Bmat, frs, wr,
                                                       muA, rstdA, Gp, Cp, bias, out);
}

// Round 5
// 105.163 us; speedup vs baseline: 1.0906x; 1.0906x over previous
//
#include <hip/hip_runtime.h>
#include <math.h>

// Problem constants (match reference)
#define B_SZ    2048
#define IN_DIM  256
#define N_RULES 128
#define OUT_DIM 64
#define D_DIM   32896          // (IN_DIM+1)*N_RULES
#define NBIG    8192           // N_RULES*OUT_DIM (n = r*64 + o)
#define KAQ     512            // Aq row: [x^2 (256) | x (256)]

typedef __attribute__((ext_vector_type(8))) short bf16x8;
typedef __attribute__((ext_vector_type(4))) float f32x4;

static __device__ __forceinline__ short f2bf(float f) {
    union { float f; unsigned u; } v; v.f = f;
    unsigned r = v.u + 0x7fffu + ((v.u >> 16) & 1u);   // RNE
    return (short)(r >> 16);
}
static __device__ __forceinline__ void gld_lds16(const short* g, short* l) {
    __builtin_amdgcn_global_load_lds((const __attribute__((address_space(1))) void*)g,
                                     (__attribute__((address_space(3))) void*)l, 16, 0, 0);
}

// ---------------------------------------------------------------------------
// abq: blocks [0,128):  Bq[r][0:256]=bf16(-s), Bq[r][256:512]=bf16(2cs), k2[r]
//      blocks [128,384): Aq[b][0:256]=bf16(x^2), Aq[b][256:512]=bf16(x)
//      (vectorized: 8 elems/thread, float4 loads, bf16x8 stores)
// ---------------------------------------------------------------------------
__global__ __launch_bounds__(256) void abq_kernel(const float* __restrict__ X,
                                                  const float* __restrict__ centers,
                                                  const float* __restrict__ sigmas,
                                                  short* __restrict__ Aq,
                                                  short* __restrict__ Bq,
                                                  float* __restrict__ k2) {
    int bid = blockIdx.x, t = threadIdx.x;
    if (bid < 128) {
        int r = bid, i = t;
        float sgm = sigmas[i * N_RULES + r];
        float s   = 0.5f / (sgm * sgm) + 1e-8f;
        float c   = centers[i * N_RULES + r];
        Bq[(size_t)r * KAQ + i]       = f2bf(-s);
        Bq[(size_t)r * KAQ + 256 + i] = f2bf(2.0f * c * s);
        __shared__ float red[256];
        red[i] = c * c * s;
        __syncthreads();
        for (int st = 128; st > 0; st >>= 1) {
            if (i < st) red[i] += red[i + st];
            __syncthreads();
        }
        if (i == 0) k2[r] = red[0];
    } else {
        int gid = (bid - 128) * 256 + t;     // 0..65535
        int i0 = gid * 8;                    // 8 consecutive elems, same X row
        int b = i0 >> 8, k = i0 & 255;
        float4 x0 = *(const float4*)(X + i0);
        float4 x1 = *(const float4*)(X + i0 + 4);
        bf16x8 q, v;
        q[0] = f2bf(x0.x * x0.x); v[0] = f2bf(x0.x);
        q[1] = f2bf(x0.y * x0.y); v[1] = f2bf(x0.y);
        q[2] = f2bf(x0.z * x0.z); v[2] = f2bf(x0.z);
        q[3] = f2bf(x0.w * x0.w); v[3] = f2bf(x0.w);
        q[4] = f2bf(x1.x * x1.x); v[4] = f2bf(x1.x);
        q[5] = f2bf(x1.y * x1.y); v[5] = f2bf(x1.y);
        q[6] = f2bf(x1.z * x1.z); v[6] = f2bf(x1.z);
        q[7] = f2bf(x1.w * x1.w); v[7] = f2bf(x1.w);
        *(bf16x8*)(Aq + (size_t)b * KAQ + k)       = q;
        *(bf16x8*)(Aq + (size_t)b * KAQ + 256 + k) = v;
    }
}

// ---------------------------------------------------------------------------
// rawprep: blocks [0,128)   — rawgemm+softmax+LN stats (16 batch rows/block);
//          blocks [128,1152) — prep (vectorized): Bmat bf16(gamma*W), Gp/Cp
//          partials, wr tail. Independent work packed into one launch so the
//          128 rawsm blocks hide under prep's 1024 bandwidth-bound blocks.
// ---------------------------------------------------------------------------
__global__ __launch_bounds__(256) void rawprep_kernel(const short* __restrict__ Aq,
                                                      const short* __restrict__ Bq,
                                                      const float* __restrict__ k2,
                                                      const float* __restrict__ X,
                                                      const float* __restrict__ gamma,
                                                      const float* __restrict__ beta,
                                                      const float* __restrict__ W,
                                                      float* __restrict__ frs,
                                                      float* __restrict__ muA,
                                                      float* __restrict__ rstdA,
                                                      short* __restrict__ Bmat,
                                                      float* __restrict__ wr,
                                                      float* __restrict__ Gp,
                                                      float* __restrict__ Cp) {
    __shared__ float S[16][132];     // rawsm scores (pad 132)
    __shared__ float sg[256], sc_[256];
    int bid = blockIdx.x, t = threadIdx.x;

    if (bid < 128) {
        // ---- rawsm: M=16,N=128,K=512 MFMA + softmax + LN stats ----
        int wave = t >> 6, lane = t & 63;
        int lrow = lane & 15, kq = lane >> 4;
        int m0 = bid * 16;

        f32x4 acc[2];
#pragma unroll
        for (int ni = 0; ni < 2; ++ni)
#pragma unroll
            for (int j = 0; j < 4; ++j) acc[ni][j] = 0.0f;

        const short* Ar = Aq + (size_t)(m0 + lrow) * KAQ + kq * 8;
        const short* Br = Bq + (size_t)(wave * 32 + lrow) * KAQ + kq * 8;
#pragma unroll
        for (int kt = 0; kt < 16; ++kt) {
            bf16x8 a = *(const bf16x8*)(Ar + kt * 32);
#pragma unroll
            for (int ni = 0; ni < 2; ++ni) {
                bf16x8 b = *(const bf16x8*)(Br + (size_t)ni * 16 * KAQ + kt * 32);
                acc[ni] = __builtin_amdgcn_mfma_f32_16x16x32_bf16(a, b, acc[ni], 0, 0, 0);
            }
        }
#pragma unroll
        for (int ni = 0; ni < 2; ++ni) {
            int col = wave * 32 + ni * 16 + lrow;
            float kk2 = k2[col];
#pragma unroll
            for (int j = 0; j < 4; ++j)
                S[kq * 4 + j][col] = (acc[ni][j] - kk2) * (1.0f / 256.0f);
        }
        __syncthreads();

#pragma unroll
        for (int rr = 0; rr < 4; ++rr) {
            int row = wave * 4 + rr;
            int b = m0 + row;
            float v0 = S[row][lane];
            float v1 = S[row][64 + lane];
            float m = fmaxf(v0, v1);
#pragma unroll
            for (int off = 32; off >= 1; off >>= 1) m = fmaxf(m, __shfl_xor(m, off));
            float e0 = expf(v0 - m), e1 = expf(v1 - m);
            float ssum = e0 + e1;
#pragma unroll
            for (int off = 32; off >= 1; off >>= 1) ssum += __shfl_xor(ssum, off);
            float inv = 1.0f / ssum;
            e0 *= inv; e1 *= inv;
            frs[(size_t)b * N_RULES + lane]      = e0;
            frs[(size_t)b * N_RULES + 64 + lane] = e1;
            float q = e0 * e0 + e1 * e1;
            float4 xv = *(const float4*)(X + (size_t)b * IN_DIM + lane * 4);
            float sx  = xv.x + xv.y + xv.z + xv.w;
            float sx2 = xv.x * xv.x + xv.y * xv.y + xv.z * xv.z + xv.w * xv.w;
#pragma unroll
            for (int off = 32; off >= 1; off >>= 1) {
                q   += __shfl_xor(q, off);
                sx  += __shfl_xor(sx, off);
                sx2 += __shfl_xor(sx2, off);
            }
            if (lane == 0) {
                float mu  = (sx + 1.0f) / (float)D_DIM;
                float var = (sx2 + 1.0f) * q / (float)D_DIM - mu * mu;
                muA[b]   = mu;
                rstdA[b] = rsqrtf(var + 1e-5f);
            }
        }
    } else {
        // ---- prep: 8 consecutive d per thread (vectorized) ----
        int pid = bid - 128;
        int c = pid & 15, o = pid >> 4;
        const float* Wo = W + (size_t)o * D_DIM;
        int d0 = c * 2048 + t * 8;
        float4 w0 = *(const float4*)(Wo + d0);
        float4 w1 = *(const float4*)(Wo + d0 + 4);
        float4 g0 = *(const float4*)(gamma + d0);
        float4 g1 = *(const float4*)(gamma + d0 + 4);
        float4 b0 = *(const float4*)(beta + d0);
        float4 b1 = *(const float4*)(beta + d0 + 4);
        float p0 = g0.x * w0.x, p1 = g0.y * w0.y, p2 = g0.z * w0.z, p3 = g0.w * w0.w;
        float p4 = g1.x * w1.x, p5 = g1.y * w1.y, p6 = g1.z * w1.z, p7 = g1.w * w1.w;
        float g = p0 + p1 + p2 + p3 + p4 + p5 + p6 + p7;
        float cc = b0.x * w0.x + b0.y * w0.y + b0.z * w0.z + b0.w * w0.w
                 + b1.x * w1.x + b1.y * w1.y + b1.z * w1.z + b1.w * w1.w;
        bf16x8 pv;
        pv[0] = f2bf(p0); pv[1] = f2bf(p1); pv[2] = f2bf(p2); pv[3] = f2bf(p3);
        pv[4] = f2bf(p4); pv[5] = f2bf(p5); pv[6] = f2bf(p6); pv[7] = f2bf(p7);
        int r = d0 >> 8, k = d0 & 255;
        *(bf16x8*)(Bmat + (size_t)((r << 6) + o) * IN_DIM + k) = pv;
        if (c == 15 && t < 128) {
            int d = 32768 + t;
            float w  = Wo[d];
            float ga = gamma[d];
            float be = beta[d];
            g += ga * w; cc += be * w;
            wr[t * 64 + o] = ga * w;
        }
        sg[t] = g; sc_[t] = cc;
        __syncthreads();
        for (int s = 128; s > 0; s >>= 1) {
            if (t < s) { sg[t] += sg[t + s]; sc_[t] += sc_[t + s]; }
            __syncthreads();
        }
        if (t == 0) { Gp[c * 64 + o] = sg[0]; Cp[c * 64 + o] = sc_[0]; }
    }
}

// ---------------------------------------------------------------------------
// fused gemm1 + weighted reduce (T never materialized), 2-phase schedule.
//   Grid (16 nc, 32 m-tiles) = 512 blocks, 2/CU (8 waves/CU); bid%8 == nc%8
//   pins each nc's 256 KB Bmat slice + Aq rows to one XCD's L2.
//   A (64 rows x full K=256, 32 KB) staged ONCE; B double-buffered
//   (2 x 128rows x 64k = 2 x 16 KB). 16 phases p = nt*4+kki: issue next
//   phase's B-stage BEFORE computing from the current buffer, then ONE
//   __syncthreads per phase — its implicit vmcnt(0) drain lands after the
//   16-MFMA compute, so the stage latency hides under compute (T3 minimum
//   2-phase recipe, no inline asm / no setprio / plain HIP). Race-free:
//   reads of a buffer always finish before the barrier preceding its
//   overwrite. At kki==3 fold acc into oacc with frs/wr (registers only).
//   wn=0/1 partials combined via LDS; one fp32 slice P[nc][64rows][64].
// ---------------------------------------------------------------------------
__global__ __launch_bounds__(256, 2) void fusedgemm_kernel(const short* __restrict__ Aq,
                                                           const short* __restrict__ Bmat,
                                                           const float* __restrict__ frs,
                                                           const float* __restrict__ wr,
                                                           float* __restrict__ P) {
    __shared__ __attribute__((aligned(16))) short As[64 * 256];      // 32 KB, full K
    __shared__ __attribute__((aligned(16))) short Bs[2][128 * 64];   // 2 x 16 KB
    __shared__ float frs_s[64][9];    // stride 9: conflict-free broadcast reads

    int nc = blockIdx.x;              // rules nc*8 .. nc*8+7
    int m0 = blockIdx.y * 64;
    int t = threadIdx.x;
    int lane = t & 63, wave = t >> 6;
    int wm = wave >> 1, wn = wave & 1;
    int lrow = lane & 15, kq = lane >> 4;

    // stage frs for 64 rows x 8 rules (prologue barrier covers the use)
    for (int u = t; u < 64 * 8; u += 256) {
        int row = u >> 3, rr = u & 7;
        frs_s[row][rr] = frs[(size_t)(m0 + row) * N_RULES + nc * 8 + rr];
    }

    // prologue: stage full A (8 sweeps, XOR swizzle over 32 granules/row)
    // and B phase 0 (4 sweeps, XOR over 8 granules/row)
#pragma unroll
    for (int s = 0; s < 8; ++s) {
        int idx = s * 256 + t;
        int row = idx >> 5, gp = idx & 31;
        int kg = gp ^ (row & 31);
        gld_lds16(Aq + (size_t)(m0 + row) * KAQ + 256 + kg * 8, As + idx * 8);
    }
#pragma unroll
    for (int s = 0; s < 4; ++s) {
        int idx = s * 256 + t;
        int row = idx >> 3, gp = idx & 7;
        int kg = gp ^ (row & 7);
        gld_lds16(Bmat + (size_t)(nc * 512 + row) * IN_DIM + kg * 8, Bs[0] + idx * 8);
    }
    __syncthreads();

    f32x4 acc[2][4], oacc[2][4];
#pragma unroll
    for (int mi = 0; mi < 2; ++mi)
#pragma unroll
        for (int ni = 0; ni < 4; ++ni)
#pragma unroll
            for (int j = 0; j < 4; ++j) { acc[mi][ni][j] = 0.0f; oacc[mi][ni][j] = 0.0f; }

#pragma unroll
    for (int p = 0; p < 16; ++p) {
        int nt = p >> 2, kki = p & 3;

        // issue next phase's B stage FIRST (overlaps with this phase's compute)
        if (p < 15) {
            int pn = p + 1;
            int n0n = nc * 512 + (pn >> 2) * 128;
            int kkn = (pn & 3) * 64;
            short* dst = Bs[pn & 1];
#pragma unroll
            for (int s = 0; s < 4; ++s) {
                int idx = s * 256 + t;
                int row = idx >> 3, gp = idx & 7;
                int kg = gp ^ (row & 7);
                gld_lds16(Bmat + (size_t)(n0n + row) * IN_DIM + kkn + kg * 8, dst + idx * 8);
            }
        }

        // compute this phase from Bs[p&1] (staged last phase, drained by the
        // barrier we crossed to get here)
        const short* Bcur = Bs[p & 1];
#pragma unroll
        for (int ks = 0; ks < 2; ++ks) {
            bf16x8 a[2], bb[4];
#pragma unroll
            for (int mi = 0; mi < 2; ++mi) {
                int row = wm * 32 + mi * 16 + lrow;
                a[mi] = *(const bf16x8*)(As + row * 256 + (((kki * 8 + ks * 4 + kq) ^ (row & 31)) * 8));
            }
#pragma unroll
            for (int ni = 0; ni < 4; ++ni) {
                int row = wn * 64 + ni * 16 + lrow;
                bb[ni] = *(const bf16x8*)(Bcur + row * 64 + (((ks * 4 + kq) ^ (row & 7)) * 8));
            }
#pragma unroll
            for (int mi = 0; mi < 2; ++mi)
#pragma unroll
                for (int ni = 0; ni < 4; ++ni)
                    acc[mi][ni] = __builtin_amdgcn_mfma_f32_16x16x32_bf16(a[mi], bb[ni], acc[mi][ni], 0, 0, 0);
        }

        if (kki == 3) {
            // fold this tile's quadrant into oacc (registers only)
            int r  = nc * 8 + nt * 2 + wn;   // this wave's rule for tile nt
            int rr = nt * 2 + wn;
#pragma unroll
            for (int ni = 0; ni < 4; ++ni) {
                int o = ni * 16 + lrow;
                float wv = wr[(size_t)r * 64 + o];
#pragma unroll
                for (int mi = 0; mi < 2; ++mi) {
#pragma unroll
                    for (int j = 0; j < 4; ++j) {
                        int row = wm * 32 + mi * 16 + kq * 4 + j;
                        oacc[mi][ni][j] += frs_s[row][rr] * (acc[mi][ni][j] + wv);
                        acc[mi][ni][j] = 0.0f;
                    }
                }
            }
        }

        // one barrier per phase: drains this phase's stage (vmcnt) and orders
        // buffer reuse for the next phase's overwrite
        __syncthreads();
    }

    // combine wn=0/wn=1 partials (same (row,o)) via LDS; write P[nc][m0+row][o].
    float* redbuf = (float*)Bs;        // [64][68] fp32 = 17.4 KB (stride 68)
    if (wn == 1) {
#pragma unroll
        for (int mi = 0; mi < 2; ++mi)
#pragma unroll
            for (int ni = 0; ni < 4; ++ni)
#pragma unroll
                for (int j = 0; j < 4; ++j) {
                    int row = wm * 32 + mi * 16 + kq * 4 + j;
                    int o   = ni * 16 + lrow;
                    redbuf[row * 68 + o] = oacc[mi][ni][j];
                }
    }
    __syncthreads();
    if (wn == 0) {
        float* Pc = P + ((size_t)nc * B_SZ + m0) * 64;
#pragma unroll
        for (int mi = 0; mi < 2; ++mi)
#pragma unroll
            for (int ni = 0; ni < 4; ++ni)
#pragma unroll
                for (int j = 0; j < 4; ++j) {
                    int row = wm * 32 + mi * 16 + kq * 4 + j;
                    int o   = ni * 16 + lrow;
                    Pc[row * 64 + o] = oacc[mi][ni][j] + redbuf[row * 68 + o];
                }
    }
}

// ---------------------------------------------------------------------------
// epilogue: out[b,o] = rstd_b*( sum_p P[p][b][o] - mu_b*G[o] ) + C[o] + bias[o]
// 4 rows/block, 512 blocks.
// ---------------------------------------------------------------------------
__global__ void epi_kernel(const float* __restrict__ P, const float* __restrict__ Gp,
                           const float* __restrict__ Cp, const float* __restrict__ bias,
                           const float* __restrict__ muA, const float* __restrict__ rstdA,
                           float* __restrict__ out) {
    int t = threadIdx.x;
    int b = blockIdx.x * 4 + (t >> 6);
    int o = t & 63;
    float S = 0.f;
#pragma unroll
    for (int p = 0; p < 16; ++p)
        S += P[((size_t)p * B_SZ + b) * 64 + o];
    float g = 0.f, cc = 0.f;
#pragma unroll
    for (int j = 0; j < 16; ++j) { g += Gp[j * 64 + o]; cc += Cp[j * 64 + o]; }
    out[(size_t)b * OUT_DIM + o] = rstdA[b] * (S - muA[b] * g) + cc + bias[o];
}

// ---------------------------------------------------------------------------
extern "C" void kernel_launch(void* const* d_in, const int* in_sizes, int n_in,
                              void* d_out, int out_size, void* d_ws, size_t ws_size,
                              hipStream_t stream) {
    const float* X       = (const float*)d_in[0];
    const float* centers = (const float*)d_in[1];
    const float* sigmas  = (const float*)d_in[2];
    const float* gamma   = (const float*)d_in[3];
    const float* beta    = (const float*)d_in[4];
    const float* W       = (const float*)d_in[5];
    const float* bias    = (const float*)d_in[6];
    float* out = (float*)d_out;

    char* w = (char*)d_ws;
    short* Aq   = (short*)w; w += (size_t)B_SZ * KAQ * 2;           // 2 MB
    short* Bmat = (short*)w; w += (size_t)NBIG * IN_DIM * 2;        // 4 MB
    float* P    = (float*)w; w += (size_t)16 * B_SZ * 64 * 4;       // 8 MB
    short* Bq   = (short*)w; w += (size_t)N_RULES * KAQ * 2;        // 128 KB
    float* frs  = (float*)w; w += (size_t)B_SZ * N_RULES * 4;       // 1 MB
    float* wr   = (float*)w; w += (size_t)NBIG * 4;
    float* k2   = (float*)w; w += (size_t)N_RULES * 4;
    float* muA  = (float*)w; w += (size_t)B_SZ * 4;
    float* rstdA= (float*)w; w += (size_t)B_SZ * 4;
    float* Gp   = (float*)w; w += (size_t)16 * 64 * 4;
    float* Cp   = (float*)w; w += (size_t)16 * 64 * 4;

    abq_kernel<<<384, 256, 0, stream>>>(X, centers, sigmas, Aq, Bq, k2);
    rawprep_kernel<<<1152, 256, 0, stream>>>(Aq, Bq, k2, X, gamma, beta, W,
                                             frs, muA, rstdA, Bmat, wr, Gp, Cp);
    fusedgemm_kernel<<<dim3(16, 32), 256, 0, stream>>>(Aq, Bmat, frs, wr, P);
    epi_kernel<<<B_SZ / 4, 256, 0, stream>>>(P, Gp, Cp, bias, muA, rstdA, out);
}